// Round 12
// baseline (1640.737 us; speedup 1.0000x reference)
//
#include <hip/hip_runtime.h>
#include <math.h>

// Problem constants (PMS_1): B=4, C=64, H=W=128
constexpr int B = 4, C = 64, H = 128, W = 128;
constexpr int HW = H * W;
constexpr size_t TOT   = (size_t)B * C * HW;  // 4,194,304 elements
constexpr float SCALE  = 1.0f / 24.0f;        // 1/sqrt(C*9)

typedef _Float16 half8 __attribute__((ext_vector_type(8)));
typedef _Float16 half4v __attribute__((ext_vector_type(4)));
typedef float floatx4 __attribute__((ext_vector_type(4)));

// fp16 weight arena. Per conv-step (one (kh,kw)): 4096 halfs,
// half idx l = (h*4+mt)*512 + q*128 + l15*8 + j
//   -> W[oc=mt*16+l15][ic=h*32+q*8+j] (* scale * cond for res convs).
// Res convs have per-sample copies (cond folded): [conv 0..17][b 0..3].
constexpr size_t A_RES = 0;                   // 18*4 x 36864
constexpr size_t A_M1  = 2654208;             // 10 x 4096
constexpr size_t A_M3  = 2695168;             // 10 x 36864
constexpr size_t A_M5  = 3063808;             // 10 x 102400
constexpr size_t A_TOT = 4087808;             // halfs (= 15968 * 256)

__global__ __launch_bounds__(256) void wt_kernel(
    const float* __restrict__ rw, const float* __restrict__ mw1,
    const float* __restrict__ mw3, const float* __restrict__ mw5,
    const float* __restrict__ cf1, const float* __restrict__ cf2,
    _Float16* __restrict__ wt)
{
    size_t e = (size_t)blockIdx.x * 256 + threadIdx.x;
    const float* src; int K; float scale; int l;
    if (e < A_M1) {
        int cb = (int)(e / 36864); l = (int)(e - (size_t)cb * 36864);
        int conv = cb >> 2, b = cb & 3;
        src = rw + (size_t)conv * 36864; K = 3;
        int icw = l & 7, l15 = (l >> 3) & 15, q = (l >> 7) & 3;
        int mt = (l >> 9) & 3, h = (l >> 11) & 1, kk = l >> 12;
        int oc = mt * 16 + l15, ic = h * 32 + q * 8 + icw;
        int kh = kk / 3, kw = kk - kh * 3;
        float cond = (conv < 10) ? cf1[(size_t)(conv * 4 + b) * 64 + ic]
                                 : cf2[(size_t)((conv - 10) * 4 + b) * 64 + ic];
        wt[e] = (_Float16)(src[((oc * C + ic) * 3 + kh) * 3 + kw] * SCALE * cond);
        return;
    } else if (e < A_M3) {
        int e2 = (int)(e - A_M1); int conv = e2 / 4096; l = e2 - conv * 4096;
        src = mw1 + (size_t)conv * 4096; K = 1; scale = 1.f;
    } else if (e < A_M5) {
        int e2 = (int)(e - A_M3); int conv = e2 / 36864; l = e2 - conv * 36864;
        src = mw3 + (size_t)conv * 36864; K = 3; scale = 1.f;
    } else {
        int e2 = (int)(e - A_M5); int conv = e2 / 102400; l = e2 - conv * 102400;
        src = mw5 + (size_t)conv * 102400; K = 5; scale = 1.f;
    }
    int j   = l & 7;
    int l15 = (l >> 3) & 15;
    int q   = (l >> 7) & 3;
    int mt  = (l >> 9) & 3;
    int h   = (l >> 11) & 1;
    int kk  = l >> 12;
    int oc = mt * 16 + l15, ic = h * 32 + q * 8 + j;
    int kh = kk / K, kw = kk - kh * K;
    wt[e] = (_Float16)(src[((oc * C + ic) * K + kh) * K + kw] * scale);
}

// x fp32 NCHW -> fp16 NHWC (channels-last), LDS transpose
__global__ __launch_bounds__(256) void xcvt_kernel(
    const float* __restrict__ x, _Float16* __restrict__ xh)
{
    __shared__ _Float16 s[64 * 72];
    const int b = blockIdx.y;
    const size_t p0 = (size_t)blockIdx.x * 64;
    const int t = threadIdx.x, px = t & 63, cg0 = t >> 6;
#pragma unroll
    for (int k = 0; k < 16; ++k) {
        int c = cg0 * 16 + k;
        s[px * 72 + c] = (_Float16)x[((size_t)(b * 64 + c)) * HW + p0 + px];
    }
    __syncthreads();
#pragma unroll
    for (int k = 0; k < 2; ++k) {
        int idx = k * 256 + t;
        int pxw = idx >> 3, o8 = idx & 7;
        uint4 v = *(const uint4*)&s[pxw * 72 + o8 * 8];
        *(uint4*)&xh[((size_t)b * HW + p0 + pxw) * 64 + o8 * 8] = v;
    }
}

// zero the 5 x (256 umax + 256 fsum) stats dwords
__global__ __launch_bounds__(256) void init_kernel(unsigned* __restrict__ st)
{
    int i = blockIdx.x * 256 + threadIdx.x;
    if (i < 5 * 512) st[i] = 0u;
}

// ---- shared device helpers ------------------------------------------------
__device__ __forceinline__ unsigned fenc(float f) {
    unsigned b = __float_as_uint(f);
    return (b & 0x80000000u) ? ~b : (b | 0x80000000u);
}
__device__ __forceinline__ float fdec(unsigned u) {
    unsigned b = (u & 0x80000000u) ? (u & 0x7fffffffu) : ~u;
    return __uint_as_float(b);
}

// Load this wave's oc-half A chunk: 4 x b128 ([h][m], oc mt = og*2+m).
__device__ __forceinline__ void loadAo(const _Float16* __restrict__ base,
                                       int og, int q, int l15, uint4* dst)
{
    const uint4* p = (const uint4*)base;
#pragma unroll
    for (int h = 0; h < 2; ++h)
#pragma unroll
        for (int m = 0; m < 2; ++m)
            dst[h * 2 + m] = p[(h * 4 + og * 2 + m) * 64 + q * 16 + l15];
}

// Read the 8 B fragments for one step into registers.
template <int IWs, int NPXP>
__device__ __forceinline__ void readB8(const unsigned* __restrict__ s_b,
    int ph, int l15, int q, int kh, int kw, int off, uint4* bf)
{
#pragma unroll
    for (int h = 0; h < 2; ++h)
#pragma unroll
        for (int ng = 0; ng < 4; ++ng) {
            int row = 4 * ph + ng + kh + off;
            int px = row * IWs + l15 + kw + off;
            bf[h * 4 + ng] = ((const uint4*)s_b)[(h * 4 + q) * NPXP + px];
        }
}

// 16 MFMA from preloaded registers.
__device__ __forceinline__ void domfma_og(const uint4* a, const uint4* bf,
                                          floatx4 (&acc)[2][4])
{
#pragma unroll
    for (int h = 0; h < 2; ++h) {
        half8 af0 = __builtin_bit_cast(half8, a[h * 2 + 0]);
        half8 af1 = __builtin_bit_cast(half8, a[h * 2 + 1]);
#pragma unroll
        for (int ng = 0; ng < 4; ++ng) {
            half8 b = __builtin_bit_cast(half8, bf[h * 4 + ng]);
            acc[0][ng] = __builtin_amdgcn_mfma_f32_16x16x32_f16(af0, b, acc[0][ng], 0, 0, 0);
            acc[1][ng] = __builtin_amdgcn_mfma_f32_16x16x32_f16(af1, b, acc[1][ng], 0, 0, 0);
        }
    }
}

// step g of the 35-step MFE sequence -> (kh,kw,off)
__device__ __forceinline__ void mfeParams(int g, int& kh, int& kw, int& off)
{
    if (g < 25)      { kh = g / 5; kw = g % 5; off = 0; }
    else if (g < 34) { int ls = g - 25; kh = ls / 3; kw = ls % 3; off = 1; }
    else             { kh = 0; kw = 0; off = 2; }
}

// ---------------------------------------------------------------------------
// Fused resblock: out = conv2(relu(conv1(in)+b0)) + b1 + in.
// 512 thr (8 waves), tile 16x16. conv1 on 18x18 halo into LDS r; conv2 reads
// r; residual from staged input. A: depth-3 register pipeline across both
// convs (18 flat steps); conv2 B: depth-2 register pipeline.
// ---------------------------------------------------------------------------
template <bool STATS>
__global__ __launch_bounds__(512, 1) void fres_kernel(
    const _Float16* __restrict__ in, const _Float16* __restrict__ w0a,
    const _Float16* __restrict__ w1a,
    const float* __restrict__ bias0, const float* __restrict__ bias1,
    unsigned* __restrict__ umax, float* __restrict__ fsum,
    _Float16* __restrict__ out)
{
    constexpr int NIN = 401;   // padded px slots, 20x20 staging
    constexpr int RNP = 329;   // padded px slots, 18x18 r
    __shared__ __align__(16) unsigned s_in[NIN * 32];
    __shared__ __align__(16) unsigned s_r[RNP * 32];
    __shared__ float s_stat[2][8][64];

    const int tid = threadIdx.x;
    const int bx = blockIdx.x, b = blockIdx.y;
    const int y0 = (bx >> 3) * 16, x0 = (bx & 7) * 16;
    const _Float16* w0 = w0a + (size_t)b * 36864;
    const _Float16* w1 = w1a + (size_t)b * 36864;
    const int lane = tid & 63, wv = tid >> 6;
    const int pg = wv & 3, og = wv >> 2;
    const int l15 = lane & 15, q = lane >> 4;

    auto aPtrF = [&](int g) -> const _Float16* {
        return (g < 9) ? w0 + (size_t)g * 4096 : w1 + (size_t)(g - 9) * 4096;
    };

    uint4 A[3][4];
    loadAo(aPtrF(0), og, q, l15, A[0]);
    loadAo(aPtrF(1), og, q, l15, A[1]);

    // ---- stage input 20x20 (origin -2), zero-padded
    for (int idx = tid; idx < 400 * 8; idx += 512) {
        int px = idx >> 3, o8 = idx & 7;
        int r = px / 20, cix = px - r * 20;
        int gy = y0 + r - 2, gx = x0 + cix - 2;
        uint4 v = {0u, 0u, 0u, 0u};
        if (gy >= 0 && gy < H && gx >= 0 && gx < W)
            v = *(const uint4*)&in[((size_t)b * HW + (size_t)gy * W + gx) * 64 + o8 * 8];
        ((uint4*)s_in)[o8 * NIN + px] = v;
    }
    __syncthreads();

    // ---- conv1 on 18x18 r-grid (origin -1): wave = 6 px-tiles x 32 oc
    int spb[6], pval[6];
#pragma unroll
    for (int t = 0; t < 6; ++t) {
        int p = (pg * 6 + t) * 16 + l15;
        pval[t] = p;
        int pc = p < 324 ? p : 0;
        int jr = pc / 18, jc = pc - jr * 18;
        spb[t] = jr * 20 + jc;
    }

    floatx4 acc1[2][6] = {};
#pragma unroll
    for (int g = 0; g < 9; ++g) {
        loadAo(aPtrF(g + 2), og, q, l15, A[(g + 2) % 3]);
        __builtin_amdgcn_sched_barrier(0);
        const uint4* cur = A[g % 3];
        const int kh = g / 3, kw = g - kh * 3;
#pragma unroll
        for (int h = 0; h < 2; ++h) {
            half8 af0 = __builtin_bit_cast(half8, cur[h * 2 + 0]);
            half8 af1 = __builtin_bit_cast(half8, cur[h * 2 + 1]);
#pragma unroll
            for (int t = 0; t < 6; ++t) {
                half8 bf = __builtin_bit_cast(half8,
                    ((const uint4*)s_in)[(h * 4 + q) * NIN + spb[t] + kh * 20 + kw]);
                acc1[0][t] = __builtin_amdgcn_mfma_f32_16x16x32_f16(af0, bf, acc1[0][t], 0, 0, 0);
                acc1[1][t] = __builtin_amdgcn_mfma_f32_16x16x32_f16(af1, bf, acc1[1][t], 0, 0, 0);
            }
        }
    }

    // ---- r = relu(acc1 + bias0), fp16 into LDS; zero outside the image
#pragma unroll
    for (int t = 0; t < 6; ++t) {
        int p = pval[t];
        if (p < 324) {
            int jr = p / 18, jc = p - jr * 18;
            bool valid = (unsigned)(y0 + jr - 1) < (unsigned)H &&
                         (unsigned)(x0 + jc - 1) < (unsigned)W;
#pragma unroll
            for (int m = 0; m < 2; ++m) {
                int oc0 = og * 32 + m * 16 + q * 4;
                float4 bv = *(const float4*)(bias0 + oc0);
                float v0 = 0.f, v1 = 0.f, v2 = 0.f, v3 = 0.f;
                if (valid) {
                    v0 = fmaxf(acc1[m][t][0] + bv.x, 0.f);
                    v1 = fmaxf(acc1[m][t][1] + bv.y, 0.f);
                    v2 = fmaxf(acc1[m][t][2] + bv.z, 0.f);
                    v3 = fmaxf(acc1[m][t][3] + bv.w, 0.f);
                }
                half4v hv = { (_Float16)v0, (_Float16)v1, (_Float16)v2, (_Float16)v3 };
                int o8r = og * 4 + m * 2 + (q >> 1);
                ((uint2*)s_r)[(o8r * RNP + p) * 2 + (q & 1)] = __builtin_bit_cast(uint2, hv);
            }
        }
    }
    __syncthreads();

    // ---- conv2 from r: wave = 4 rows (pg*4+ng) x 32 oc. A pipeline
    // continues (flat steps 9..17); B double-buffered in registers.
    auto readB2 = [&](int kh, int kw, uint4* bf) {
#pragma unroll
        for (int h = 0; h < 2; ++h)
#pragma unroll
            for (int ng = 0; ng < 4; ++ng) {
                int sp = (pg * 4 + ng + kh) * 18 + l15 + kw;
                bf[h * 4 + ng] = ((const uint4*)s_r)[(h * 4 + q) * RNP + sp];
            }
    };

    floatx4 acc2[2][4] = {};
    uint4 BF[2][8];
    readB2(0, 0, BF[1]);     // step 9 parity: 9&1 = 1
#pragma unroll
    for (int g = 9; g < 18; ++g) {
        if (g + 2 < 18) loadAo(aPtrF(g + 2), og, q, l15, A[(g + 2) % 3]);
        if (g + 1 < 18) {
            int ls = g + 1 - 9;
            readB2(ls / 3, ls % 3, BF[(g + 1) & 1]);
        }
        __builtin_amdgcn_sched_barrier(0);
        domfma_og(A[g % 3], BF[g & 1], acc2);
    }

    // ---- epilogue: + bias1 + residual(from s_in), store; optional stats
    float lmax[2][4], lsum[2][4];
    if (STATS) {
#pragma unroll
        for (int m = 0; m < 2; ++m)
#pragma unroll
            for (int r = 0; r < 4; ++r) { lmax[m][r] = -INFINITY; lsum[m][r] = 0.f; }
    }
#pragma unroll
    for (int m = 0; m < 2; ++m) {
        const int oc0 = og * 32 + m * 16 + q * 4;
        const float4 bv = *(const float4*)(bias1 + oc0);
        const int o8r = og * 4 + m * 2 + (q >> 1);
#pragma unroll
        for (int ng = 0; ng < 4; ++ng) {
            const int row = pg * 4 + ng;
            const int spres = (row + 2) * 20 + l15 + 2;
            uint2 ru = ((const uint2*)s_in)[(o8r * NIN + spres) * 2 + (q & 1)];
            half4v rv = __builtin_bit_cast(half4v, ru);
            float v[4];
            v[0] = acc2[m][ng][0] + bv.x + (float)rv[0];
            v[1] = acc2[m][ng][1] + bv.y + (float)rv[1];
            v[2] = acc2[m][ng][2] + bv.z + (float)rv[2];
            v[3] = acc2[m][ng][3] + bv.w + (float)rv[3];
            const size_t off = ((size_t)b * HW + (size_t)(y0 + row) * W + x0 + l15) * 64 + oc0;
            half4v hv = { (_Float16)v[0], (_Float16)v[1], (_Float16)v[2], (_Float16)v[3] };
            *(half4v*)&out[off] = hv;
            if (STATS) {
#pragma unroll
                for (int r = 0; r < 4; ++r) {
                    lmax[m][r] = fmaxf(lmax[m][r], v[r]);
                    lsum[m][r] += v[r];
                }
            }
        }
    }
    if (STATS) {
#pragma unroll
        for (int msk = 1; msk < 16; msk <<= 1) {
#pragma unroll
            for (int m = 0; m < 2; ++m)
#pragma unroll
                for (int r = 0; r < 4; ++r) {
                    lmax[m][r] = fmaxf(lmax[m][r], __shfl_xor(lmax[m][r], msk));
                    lsum[m][r] += __shfl_xor(lsum[m][r], msk);
                }
        }
        if (l15 == 0) {
#pragma unroll
            for (int m = 0; m < 2; ++m)
#pragma unroll
                for (int r = 0; r < 4; ++r) {
                    int oc = og * 32 + m * 16 + q * 4 + r;
                    s_stat[0][wv][oc] = lmax[m][r];
                    s_stat[1][wv][oc] = lsum[m][r];
                }
        }
        __syncthreads();
        if (tid < 64) {
            int oc = tid;
            int w0i = (oc < 32) ? 0 : 4;
            float mv = s_stat[0][w0i][oc], sv = s_stat[1][w0i][oc];
#pragma unroll
            for (int k = 1; k < 4; ++k) {
                mv = fmaxf(mv, s_stat[0][w0i + k][oc]);
                sv += s_stat[1][w0i + k][oc];
            }
            atomicMax(&umax[b * 64 + oc], fenc(mv));
            atomicAdd(&fsum[b * 64 + oc], sv);
        }
    }
}

// ---------------------------------------------------------------------------
// MFE branch-1 fused, oc-split, fully software-pipelined: A depth-3 + B
// depth-2 register buffers across all 35 steps (B window staged once, so
// B-prefetch legally crosses the phase epilogues).
// ---------------------------------------------------------------------------
__global__ __launch_bounds__(256, 2) void mfe1_kernel(
    const _Float16* __restrict__ in,
    const _Float16* __restrict__ w5, const _Float16* __restrict__ w3,
    const _Float16* __restrict__ w1,
    const float* __restrict__ b5, const float* __restrict__ b3,
    const float* __restrict__ b1,
    _Float16* __restrict__ t5, _Float16* __restrict__ t3, _Float16* __restrict__ t1)
{
    constexpr int IWs = 20, NPX = 240, NPXP = 241;
    __shared__ __align__(16) unsigned int s_b[NPXP * 32];

    const int tid = threadIdx.x;
    const int bx = blockIdx.x, b = blockIdx.y;
    const int y0 = (bx >> 3) * 8, x0 = (bx & 7) * 16;
    const int lane = tid & 63, wv = tid >> 6;
    const int ph = wv & 1, og = wv >> 1;
    const int l15 = lane & 15, q = lane >> 4;

    auto aPtr = [&](int g) -> const _Float16* {
        if (g < 25) return w5 + (size_t)g * 4096;
        if (g < 34) return w3 + (size_t)(g - 25) * 4096;
        return w1;
    };

    uint4 A[3][4];
    loadAo(aPtr(0), og, q, l15, A[0]);
    loadAo(aPtr(1), og, q, l15, A[1]);

    for (int idx = tid; idx < NPX * 8; idx += 256) {
        int px = idx >> 3, o8 = idx & 7;
        int r = px / IWs, cix = px - r * IWs;
        int gy = y0 + r - 2, gx = x0 + cix - 2;
        uint4 v = {0u, 0u, 0u, 0u};
        if (gy >= 0 && gy < H && gx >= 0 && gx < W)
            v = *(const uint4*)&in[((size_t)b * HW + (size_t)gy * W + gx) * 64 + o8 * 8];
        ((uint4*)s_b)[o8 * NPXP + px] = v;
    }
    __syncthreads();

    floatx4 acc[2][4] = {};
    const floatx4 z4 = {0.f, 0.f, 0.f, 0.f};
    uint4 BF[2][8];
    readB8<IWs, NPXP>(s_b, ph, l15, q, 0, 0, 0, BF[0]);

    auto epi = [&](const float* bias, _Float16* outp, bool reset) {
#pragma unroll
        for (int m = 0; m < 2; ++m) {
            const int oc0 = og * 32 + m * 16 + q * 4;
            const float4 bv = *(const float4*)(bias + oc0);
#pragma unroll
            for (int ng = 0; ng < 4; ++ng) {
                const int y = y0 + 4 * ph + ng, x = x0 + l15;
                const size_t off = ((size_t)b * HW + (size_t)y * W + x) * 64 + oc0;
                float v[4] = { acc[m][ng][0] + bv.x, acc[m][ng][1] + bv.y,
                               acc[m][ng][2] + bv.z, acc[m][ng][3] + bv.w };
#pragma unroll
                for (int r = 0; r < 4; ++r) v[r] = v[r] > 0.f ? v[r] : 0.01f * v[r];
                half4v hv = { (_Float16)v[0], (_Float16)v[1], (_Float16)v[2], (_Float16)v[3] };
                *(half4v*)&outp[off] = hv;
                if (reset) acc[m][ng] = z4;
            }
        }
    };

#pragma unroll
    for (int g = 0; g < 35; ++g) {
        if (g + 2 < 35) loadAo(aPtr(g + 2), og, q, l15, A[(g + 2) % 3]);
        if (g + 1 < 35) {
            int kh, kw, off;
            mfeParams(g + 1, kh, kw, off);
            readB8<IWs, NPXP>(s_b, ph, l15, q, kh, kw, off, BF[(g + 1) & 1]);
        }
        __builtin_amdgcn_sched_barrier(0);
        domfma_og(A[g % 3], BF[g & 1], acc);
        if (g == 24)      epi(b5, t5, true);
        else if (g == 33) epi(b3, t3, true);
        else if (g == 34) epi(b1, t1, false);
    }
}

// ---------------------------------------------------------------------------
// MFE branch-2 fused + channel gate, oc-split, software-pipelined within
// each phase (B re-staged between phases). Stats from fused-res atomics.
// ---------------------------------------------------------------------------
__global__ __launch_bounds__(256, 2) void mfe2_kernel(
    const _Float16* __restrict__ t5in, const _Float16* __restrict__ t3in,
    const _Float16* __restrict__ t1in,
    const _Float16* __restrict__ w5, const _Float16* __restrict__ w3,
    const _Float16* __restrict__ w1,
    const float* __restrict__ b5, const float* __restrict__ b3,
    const float* __restrict__ b1,
    const unsigned* __restrict__ umax, const float* __restrict__ fsum,
    const float* __restrict__ caw1, const float* __restrict__ caw2,
    const float* __restrict__ fcwj, const float* __restrict__ fcbj,
    _Float16* __restrict__ o)
{
    constexpr int IWs = 20, NPX = 240, NPXP = 241;
    __shared__ __align__(16) unsigned int s_b[NPXP * 32];
    __shared__ float s_hid[8];

    const int tid = threadIdx.x;
    const int bx = blockIdx.x, b = blockIdx.y;
    const int y0 = (bx >> 3) * 8, x0 = (bx & 7) * 16;
    const int lane = tid & 63, wv = tid >> 6;
    const int ph = wv & 1, og = wv >> 1;
    const int l15 = lane & 15, q = lane >> 4;

    auto stageB = [&](const _Float16* __restrict__ src) {
        for (int idx = tid; idx < NPX * 8; idx += 256) {
            int px = idx >> 3, o8 = idx & 7;
            int r = px / IWs, cix = px - r * IWs;
            int gy = y0 + r - 2, gx = x0 + cix - 2;
            uint4 v = {0u, 0u, 0u, 0u};
            if (gy >= 0 && gy < H && gx >= 0 && gx < W)
                v = *(const uint4*)&src[((size_t)b * HW + (size_t)gy * W + gx) * 64 + o8 * 8];
            ((uint4*)s_b)[o8 * NPXP + px] = v;
        }
    };

    auto aPtr = [&](int g) -> const _Float16* {
        if (g < 25) return w5 + (size_t)g * 4096;
        if (g < 34) return w3 + (size_t)(g - 25) * 4096;
        return w1;
    };

    uint4 A[3][4];
    loadAo(aPtr(0), og, q, l15, A[0]);
    loadAo(aPtr(1), og, q, l15, A[1]);

    stageB(t5in);
    if (tid < 8) {
        int which = tid >> 2, hh = tid & 3;
        float s = 0.f;
        for (int i = 0; i < 64; ++i) {
            float val = which ? (fsum[b * 64 + i] * (1.f / HW)) : fdec(umax[b * 64 + i]);
            s += caw1[hh * 64 + i] * val;
        }
        s_hid[tid] = fmaxf(s, 0.f);
    }
    __syncthreads();

    floatx4 acc[2][4] = {};
    uint4 BF[2][8];

    // K5 phase: steps 0..24
    readB8<IWs, NPXP>(s_b, ph, l15, q, 0, 0, 0, BF[0]);
#pragma unroll
    for (int g = 0; g < 25; ++g) {
        loadAo(aPtr(g + 2), og, q, l15, A[(g + 2) % 3]);
        if (g + 1 < 25)
            readB8<IWs, NPXP>(s_b, ph, l15, q, (g + 1) / 5, (g + 1) % 5, 0, BF[(g + 1) & 1]);
        __builtin_amdgcn_sched_barrier(0);
        domfma_og(A[g % 3], BF[g & 1], acc);
    }
    __syncthreads();
    stageB(t3in);
    __syncthreads();
    // K3 phase: steps 25..33
    readB8<IWs, NPXP>(s_b, ph, l15, q, 0, 0, 1, BF[1]);
#pragma unroll
    for (int g = 25; g < 34; ++g) {
        if (g + 2 < 35) loadAo(aPtr(g + 2), og, q, l15, A[(g + 2) % 3]);
        if (g + 1 < 34) {
            int ls = g + 1 - 25;
            readB8<IWs, NPXP>(s_b, ph, l15, q, ls / 3, ls % 3, 1, BF[(g + 1) & 1]);
        }
        __builtin_amdgcn_sched_barrier(0);
        domfma_og(A[g % 3], BF[g & 1], acc);
    }
    __syncthreads();
    stageB(t1in);
    __syncthreads();
    // K1 step 34
    readB8<IWs, NPXP>(s_b, ph, l15, q, 0, 0, 2, BF[0]);
    domfma_og(A[34 % 3], BF[0], acc);

    // epilogue: Cg from SE hidden + FC1, then o = Cg*(acc + b5+b3+b1)
    float hs[4];
#pragma unroll
    for (int hh = 0; hh < 4; ++hh) hs[hh] = s_hid[hh] + s_hid[4 + hh];
    const float fw0 = fcwj[0], fw1 = fcwj[1], fb0 = fcbj[0], fb1 = fcbj[1];
#pragma unroll
    for (int m = 0; m < 2; ++m) {
        const int oc0 = og * 32 + m * 16 + q * 4;
        const float4 bv5 = *(const float4*)(b5 + oc0);
        const float4 bv3 = *(const float4*)(b3 + oc0);
        const float4 bv1 = *(const float4*)(b1 + oc0);
        float bs[4] = { bv5.x + bv3.x + bv1.x, bv5.y + bv3.y + bv1.y,
                        bv5.z + bv3.z + bv1.z, bv5.w + bv3.w + bv1.w };
        float cg[4];
#pragma unroll
        for (int r = 0; r < 4; ++r) {
            const float4 w2 = *(const float4*)(caw2 + (oc0 + r) * 4);
            float s = w2.x * hs[0] + w2.y * hs[1] + w2.z * hs[2] + w2.w * hs[3];
            float xll = 1.f / (1.f + expf(-s));
            cg[r] = fw1 * (fw0 * xll + fb0) + fb1;
        }
#pragma unroll
        for (int ng = 0; ng < 4; ++ng) {
            const int y = y0 + 4 * ph + ng, x = x0 + l15;
            const size_t off = ((size_t)b * HW + (size_t)y * W + x) * 64 + oc0;
            float v[4];
#pragma unroll
            for (int r = 0; r < 4; ++r) v[r] = (acc[m][ng][r] + bs[r]) * cg[r];
            half4v hv = { (_Float16)v[0], (_Float16)v[1], (_Float16)v[2], (_Float16)v[3] };
            *(half4v*)&o[off] = hv;
        }
    }
}

// out(fp32 NCHW) = o(fp16 NHWC) * map + x, LDS transpose
__global__ __launch_bounds__(256) void final_kernel(
    const _Float16* __restrict__ o, const float* __restrict__ mapp,
    const float* __restrict__ x, float* __restrict__ out)
{
    __shared__ _Float16 s[64 * 72];
    const int b = blockIdx.y;
    const size_t p0 = (size_t)blockIdx.x * 64;
    const int t = threadIdx.x;
#pragma unroll
    for (int k = 0; k < 2; ++k) {
        int idx = k * 256 + t;
        int pxw = idx >> 3, o8 = idx & 7;
        uint4 v = *(const uint4*)&o[((size_t)b * HW + p0 + pxw) * 64 + o8 * 8];
        *(uint4*)&s[pxw * 72 + o8 * 8] = v;
    }
    __syncthreads();
    const int px = t & 63, cg0 = t >> 6;
    const float mv = mapp[(size_t)b * HW + p0 + px];
#pragma unroll
    for (int k = 0; k < 16; ++k) {
        int c = cg0 * 16 + k;
        size_t off = ((size_t)(b * 64 + c)) * HW + p0 + px;
        out[off] = (float)s[px * 72 + c] * mv + x[off];
    }
}

extern "C" void kernel_launch(void* const* d_in, const int* in_sizes, int n_in,
                              void* d_out, int out_size, void* d_ws, size_t ws_size,
                              hipStream_t stream)
{
    const float* x    = (const float*)d_in[0];
    const float* cf1  = (const float*)d_in[1];
    const float* cf2  = (const float*)d_in[2];
    const float* mapp = (const float*)d_in[3];
    const float* rw   = (const float*)d_in[4];
    const float* rb   = (const float*)d_in[5];
    const float* mw1  = (const float*)d_in[6];
    const float* mb1  = (const float*)d_in[7];
    const float* mw3  = (const float*)d_in[8];
    const float* mb3  = (const float*)d_in[9];
    const float* mw5  = (const float*)d_in[10];
    const float* mb5  = (const float*)d_in[11];
    const float* caw1 = (const float*)d_in[12];
    const float* caw2 = (const float*)d_in[13];
    const float* fcw  = (const float*)d_in[14];
    const float* fcb  = (const float*)d_in[15];
    float* out = (float*)d_out;

    _Float16* wta = (_Float16*)d_ws;
    _Float16* hb  = wta + A_TOT;
    _Float16* xh  = hb;              // input; reused as t1 after resblock 0
    _Float16* bA  = hb + TOT;
    _Float16* bB  = hb + 2 * TOT;
    _Float16* t5  = hb + 3 * TOT;
    _Float16* t3  = hb + 4 * TOT;
    unsigned* stat = (unsigned*)(hb + 5 * TOT);  // 5 x (256 umax + 256 fsum)

    wt_kernel<<<dim3((unsigned)(A_TOT / 256)), 256, 0, stream>>>(rw, mw1, mw3, mw5, cf1, cf2, wta);
    init_kernel<<<dim3(10), 256, 0, stream>>>(stat);
    xcvt_kernel<<<dim3(256, B), 256, 0, stream>>>(x, xh);

    const dim3 fgrid(64, B);    // 8x8 tiles of 16x16
    const dim3 mgrid(128, B);   // 16x8 tiles of 8x16

    const _Float16* cur = xh;
    int mfe_j = 0;
    for (int i = 0; i < 9; ++i) {
        _Float16* nxt = (i & 1) ? bB : bA;
        bool isMfe = (i == 1 || i == 3 || i == 5 || i == 7 || i == 8);
        const _Float16* w0a = wta + A_RES + (size_t)(i * 2 + 0) * 4 * 36864;
        const _Float16* w1a = wta + A_RES + (size_t)(i * 2 + 1) * 4 * 36864;
        unsigned* um = stat + (size_t)mfe_j * 512;
        float* fs = (float*)(stat + (size_t)mfe_j * 512 + 256);
        if (isMfe)
            fres_kernel<true><<<fgrid, 512, 0, stream>>>(
                cur, w0a, w1a, rb + (i * 2 + 0) * C, rb + (i * 2 + 1) * C, um, fs, nxt);
        else
            fres_kernel<false><<<fgrid, 512, 0, stream>>>(
                cur, w0a, w1a, rb + (i * 2 + 0) * C, rb + (i * 2 + 1) * C, nullptr, nullptr, nxt);
        cur = nxt;

        if (isMfe) {
            int j = mfe_j++;
            mfe1_kernel<<<mgrid, 256, 0, stream>>>(
                cur,
                wta + A_M5 + (size_t)(j * 2 + 0) * 102400,
                wta + A_M3 + (size_t)(j * 2 + 0) * 36864,
                wta + A_M1 + (size_t)(j * 2 + 0) * 4096,
                mb5 + (j * 2 + 0) * C, mb3 + (j * 2 + 0) * C, mb1 + (j * 2 + 0) * C,
                t5, t3, xh);
            mfe2_kernel<<<mgrid, 256, 0, stream>>>(
                t5, t3, xh,
                wta + A_M5 + (size_t)(j * 2 + 1) * 102400,
                wta + A_M3 + (size_t)(j * 2 + 1) * 36864,
                wta + A_M1 + (size_t)(j * 2 + 1) * 4096,
                mb5 + (j * 2 + 1) * C, mb3 + (j * 2 + 1) * C, mb1 + (j * 2 + 1) * C,
                um, fs, caw1 + j * 4 * C, caw2 + j * C * 4,
                fcw + j * 2, fcb + j * 2, (_Float16*)cur);
        }
    }
    final_kernel<<<dim3(256, B), 256, 0, stream>>>(cur, mapp, x, out);
}

// Round 13
// 517.334 us; speedup vs baseline: 3.1715x; 3.1715x over previous
//
#include <hip/hip_runtime.h>
#include <math.h>

// Problem constants (PMS_1): B=4, C=64, H=W=128
constexpr int B = 4, C = 64, H = 128, W = 128;
constexpr int HW = H * W;
constexpr size_t TOT   = (size_t)B * C * HW;  // 4,194,304 elements
constexpr float SCALE  = 1.0f / 24.0f;        // 1/sqrt(C*9)

typedef _Float16 half8 __attribute__((ext_vector_type(8)));
typedef _Float16 half4v __attribute__((ext_vector_type(4)));
typedef float floatx4 __attribute__((ext_vector_type(4)));

// fp16 weight arena. Per conv-step (one (kh,kw)): 4096 halfs,
// half idx l = (h*4+mt)*512 + q*128 + l15*8 + j
//   -> W[oc=mt*16+l15][ic=h*32+q*8+j] (* scale * cond for res convs).
// Res convs have per-sample copies (cond folded): [conv 0..17][b 0..3].
constexpr size_t A_RES = 0;                   // 18*4 x 36864
constexpr size_t A_M1  = 2654208;             // 10 x 4096
constexpr size_t A_M3  = 2695168;             // 10 x 36864
constexpr size_t A_M5  = 3063808;             // 10 x 102400
constexpr size_t A_TOT = 4087808;             // halfs (= 15968 * 256)

__global__ __launch_bounds__(256) void wt_kernel(
    const float* __restrict__ rw, const float* __restrict__ mw1,
    const float* __restrict__ mw3, const float* __restrict__ mw5,
    const float* __restrict__ cf1, const float* __restrict__ cf2,
    _Float16* __restrict__ wt)
{
    size_t e = (size_t)blockIdx.x * 256 + threadIdx.x;
    const float* src; int K; float scale; int l;
    if (e < A_M1) {
        int cb = (int)(e / 36864); l = (int)(e - (size_t)cb * 36864);
        int conv = cb >> 2, b = cb & 3;
        src = rw + (size_t)conv * 36864; K = 3;
        int icw = l & 7, l15 = (l >> 3) & 15, q = (l >> 7) & 3;
        int mt = (l >> 9) & 3, h = (l >> 11) & 1, kk = l >> 12;
        int oc = mt * 16 + l15, ic = h * 32 + q * 8 + icw;
        int kh = kk / 3, kw = kk - kh * 3;
        float cond = (conv < 10) ? cf1[(size_t)(conv * 4 + b) * 64 + ic]
                                 : cf2[(size_t)((conv - 10) * 4 + b) * 64 + ic];
        wt[e] = (_Float16)(src[((oc * C + ic) * 3 + kh) * 3 + kw] * SCALE * cond);
        return;
    } else if (e < A_M3) {
        int e2 = (int)(e - A_M1); int conv = e2 / 4096; l = e2 - conv * 4096;
        src = mw1 + (size_t)conv * 4096; K = 1; scale = 1.f;
    } else if (e < A_M5) {
        int e2 = (int)(e - A_M3); int conv = e2 / 36864; l = e2 - conv * 36864;
        src = mw3 + (size_t)conv * 36864; K = 3; scale = 1.f;
    } else {
        int e2 = (int)(e - A_M5); int conv = e2 / 102400; l = e2 - conv * 102400;
        src = mw5 + (size_t)conv * 102400; K = 5; scale = 1.f;
    }
    int j   = l & 7;
    int l15 = (l >> 3) & 15;
    int q   = (l >> 7) & 3;
    int mt  = (l >> 9) & 3;
    int h   = (l >> 11) & 1;
    int kk  = l >> 12;
    int oc = mt * 16 + l15, ic = h * 32 + q * 8 + j;
    int kh = kk / K, kw = kk - kh * K;
    wt[e] = (_Float16)(src[((oc * C + ic) * K + kh) * K + kw] * scale);
}

// x fp32 NCHW -> fp16 NHWC (channels-last), LDS transpose
__global__ __launch_bounds__(256) void xcvt_kernel(
    const float* __restrict__ x, _Float16* __restrict__ xh)
{
    __shared__ _Float16 s[64 * 72];
    const int b = blockIdx.y;
    const size_t p0 = (size_t)blockIdx.x * 64;
    const int t = threadIdx.x, px = t & 63, cg0 = t >> 6;
#pragma unroll
    for (int k = 0; k < 16; ++k) {
        int c = cg0 * 16 + k;
        s[px * 72 + c] = (_Float16)x[((size_t)(b * 64 + c)) * HW + p0 + px];
    }
    __syncthreads();
#pragma unroll
    for (int k = 0; k < 2; ++k) {
        int idx = k * 256 + t;
        int pxw = idx >> 3, o8 = idx & 7;
        uint4 v = *(const uint4*)&s[pxw * 72 + o8 * 8];
        *(uint4*)&xh[((size_t)b * HW + p0 + pxw) * 64 + o8 * 8] = v;
    }
}

// zero the 5 x (256 umax + 256 fsum) stats dwords
__global__ __launch_bounds__(256) void init_kernel(unsigned* __restrict__ st)
{
    int i = blockIdx.x * 256 + threadIdx.x;
    if (i < 5 * 512) st[i] = 0u;
}

// ---- shared device helpers ------------------------------------------------
// orderable-uint encode/decode for fp32 atomic max
__device__ __forceinline__ unsigned fenc(float f) {
    unsigned b = __float_as_uint(f);
    return (b & 0x80000000u) ? ~b : (b | 0x80000000u);
}
__device__ __forceinline__ float fdec(unsigned u) {
    unsigned b = (u & 0x80000000u) ? (u & 0x7fffffffu) : ~u;
    return __uint_as_float(b);
}

// Load this wave's oc-half A chunk: 4 x b128 ([h][m], oc mt = og*2+m).
__device__ __forceinline__ void loadAo(const _Float16* __restrict__ base,
                                       int og, int q, int l15, uint4* dst)
{
    const uint4* p = (const uint4*)base;
#pragma unroll
    for (int h = 0; h < 2; ++h)
#pragma unroll
        for (int m = 0; m < 2; ++m)
            dst[h * 2 + m] = p[(h * 4 + og * 2 + m) * 64 + q * 16 + l15];
}

// One K-step, oc-split: 32 oc x 64 px x 64 ic per wave, 16 MFMA.
template <int IWs, int NPXP>
__device__ __forceinline__ void mstep_og(const unsigned int* __restrict__ s_b,
    const uint4* a, floatx4 (&acc)[2][4], int ph, int l15, int q,
    int kh, int kw, int off)
{
#pragma unroll
    for (int h = 0; h < 2; ++h) {
        half8 af0 = __builtin_bit_cast(half8, a[h * 2 + 0]);
        half8 af1 = __builtin_bit_cast(half8, a[h * 2 + 1]);
#pragma unroll
        for (int ng = 0; ng < 4; ++ng) {
            int row = 4 * ph + ng + kh + off;
            int px = row * IWs + l15 + kw + off;
            half8 bf = __builtin_bit_cast(half8, ((const uint4*)s_b)[(h * 4 + q) * NPXP + px]);
            acc[0][ng] = __builtin_amdgcn_mfma_f32_16x16x32_f16(af0, bf, acc[0][ng], 0, 0, 0);
            acc[1][ng] = __builtin_amdgcn_mfma_f32_16x16x32_f16(af1, bf, acc[1][ng], 0, 0, 0);
        }
    }
}

// ---------------------------------------------------------------------------
// Fused resblock: out = conv2(relu(conv1(in)+b0)) + b1 + in.
// 512 thr (8 waves), tile 16x16. conv1 computed on 18x18 (halo) into LDS r;
// conv2 reads r; residual from the staged input tile. Wave = (pg px-quarter,
// og oc-half); no cross-wave reduction. Optional fused channel-attention
// stats (max/mean per (b,oc)) via atomics.
// ---------------------------------------------------------------------------
template <bool STATS>
__global__ __launch_bounds__(512, 1) void fres_kernel(
    const _Float16* __restrict__ in, const _Float16* __restrict__ w0a,
    const _Float16* __restrict__ w1a,
    const float* __restrict__ bias0, const float* __restrict__ bias1,
    unsigned* __restrict__ umax, float* __restrict__ fsum,
    _Float16* __restrict__ out)
{
    constexpr int NIN = 401;   // padded px slots, 20x20 staging
    constexpr int RNP = 329;   // padded px slots, 18x18 r
    __shared__ __align__(16) unsigned s_in[NIN * 32];
    __shared__ __align__(16) unsigned s_r[RNP * 32];
    __shared__ float s_stat[2][8][64];

    const int tid = threadIdx.x;
    const int bx = blockIdx.x, b = blockIdx.y;
    const int y0 = (bx >> 3) * 16, x0 = (bx & 7) * 16;
    const _Float16* w0 = w0a + (size_t)b * 36864;
    const _Float16* w1 = w1a + (size_t)b * 36864;
    const int lane = tid & 63, wv = tid >> 6;
    const int pg = wv & 3, og = wv >> 2;
    const int l15 = lane & 15, q = lane >> 4;

    uint4 a0[4], a1[4];
    loadAo(w0, og, q, l15, a0);

    // ---- stage input 20x20 (origin -2), zero-padded
    for (int idx = tid; idx < 400 * 8; idx += 512) {
        int px = idx >> 3, o8 = idx & 7;
        int r = px / 20, cix = px - r * 20;
        int gy = y0 + r - 2, gx = x0 + cix - 2;
        uint4 v = {0u, 0u, 0u, 0u};
        if (gy >= 0 && gy < H && gx >= 0 && gx < W)
            v = *(const uint4*)&in[((size_t)b * HW + (size_t)gy * W + gx) * 64 + o8 * 8];
        ((uint4*)s_in)[o8 * NIN + px] = v;
    }
    __syncthreads();

    // ---- conv1 on 18x18 r-grid (origin -1): wave = 6 px-tiles x 32 oc
    int spb[6], pval[6];
#pragma unroll
    for (int t = 0; t < 6; ++t) {
        int p = (pg * 6 + t) * 16 + l15;
        pval[t] = p;
        int pc = p < 324 ? p : 0;
        int jr = pc / 18, jc = pc - jr * 18;
        spb[t] = jr * 20 + jc;
    }

    floatx4 acc1[2][6] = {};
#pragma unroll
    for (int g = 0; g < 9; ++g) {
        uint4* cur = (g & 1) ? a1 : a0;
        uint4* nxt = (g & 1) ? a0 : a1;
        const _Float16* np = (g < 8) ? w0 + (size_t)(g + 1) * 4096 : w1;
        loadAo(np, og, q, l15, nxt);
        __builtin_amdgcn_sched_barrier(0);
        const int kh = g / 3, kw = g - kh * 3;
#pragma unroll
        for (int h = 0; h < 2; ++h) {
            half8 af0 = __builtin_bit_cast(half8, cur[h * 2 + 0]);
            half8 af1 = __builtin_bit_cast(half8, cur[h * 2 + 1]);
#pragma unroll
            for (int t = 0; t < 6; ++t) {
                half8 bf = __builtin_bit_cast(half8,
                    ((const uint4*)s_in)[(h * 4 + q) * NIN + spb[t] + kh * 20 + kw]);
                acc1[0][t] = __builtin_amdgcn_mfma_f32_16x16x32_f16(af0, bf, acc1[0][t], 0, 0, 0);
                acc1[1][t] = __builtin_amdgcn_mfma_f32_16x16x32_f16(af1, bf, acc1[1][t], 0, 0, 0);
            }
        }
    }

    // ---- r = relu(acc1 + bias0), fp16 into LDS; zero outside the image
#pragma unroll
    for (int t = 0; t < 6; ++t) {
        int p = pval[t];
        if (p < 324) {
            int jr = p / 18, jc = p - jr * 18;
            bool valid = (unsigned)(y0 + jr - 1) < (unsigned)H &&
                         (unsigned)(x0 + jc - 1) < (unsigned)W;
#pragma unroll
            for (int m = 0; m < 2; ++m) {
                int oc0 = og * 32 + m * 16 + q * 4;
                float4 bv = *(const float4*)(bias0 + oc0);
                float v0 = 0.f, v1 = 0.f, v2 = 0.f, v3 = 0.f;
                if (valid) {
                    v0 = fmaxf(acc1[m][t][0] + bv.x, 0.f);
                    v1 = fmaxf(acc1[m][t][1] + bv.y, 0.f);
                    v2 = fmaxf(acc1[m][t][2] + bv.z, 0.f);
                    v3 = fmaxf(acc1[m][t][3] + bv.w, 0.f);
                }
                half4v hv = { (_Float16)v0, (_Float16)v1, (_Float16)v2, (_Float16)v3 };
                int o8r = og * 4 + m * 2 + (q >> 1);
                ((uint2*)s_r)[(o8r * RNP + p) * 2 + (q & 1)] = __builtin_bit_cast(uint2, hv);
            }
        }
    }
    __syncthreads();

    // ---- conv2 from r: wave = 4 rows (pg*4+ng) x 32 oc; A parity continues
    floatx4 acc2[2][4] = {};
#pragma unroll
    for (int g = 0; g < 9; ++g) {
        uint4* cur = (g & 1) ? a0 : a1;
        uint4* nxt = (g & 1) ? a1 : a0;
        if (g < 8) {
            loadAo(w1 + (size_t)(g + 1) * 4096, og, q, l15, nxt);
            __builtin_amdgcn_sched_barrier(0);
        }
        const int kh = g / 3, kw = g - kh * 3;
#pragma unroll
        for (int h = 0; h < 2; ++h) {
            half8 af0 = __builtin_bit_cast(half8, cur[h * 2 + 0]);
            half8 af1 = __builtin_bit_cast(half8, cur[h * 2 + 1]);
#pragma unroll
            for (int ng = 0; ng < 4; ++ng) {
                int sp = (pg * 4 + ng + kh) * 18 + l15 + kw;
                half8 bf = __builtin_bit_cast(half8, ((const uint4*)s_r)[(h * 4 + q) * RNP + sp]);
                acc2[0][ng] = __builtin_amdgcn_mfma_f32_16x16x32_f16(af0, bf, acc2[0][ng], 0, 0, 0);
                acc2[1][ng] = __builtin_amdgcn_mfma_f32_16x16x32_f16(af1, bf, acc2[1][ng], 0, 0, 0);
            }
        }
    }

    // ---- epilogue: + bias1 + residual(from s_in), store; optional stats
    float lmax[2][4], lsum[2][4];
    if (STATS) {
#pragma unroll
        for (int m = 0; m < 2; ++m)
#pragma unroll
            for (int r = 0; r < 4; ++r) { lmax[m][r] = -INFINITY; lsum[m][r] = 0.f; }
    }
#pragma unroll
    for (int m = 0; m < 2; ++m) {
        const int oc0 = og * 32 + m * 16 + q * 4;
        const float4 bv = *(const float4*)(bias1 + oc0);
        const int o8r = og * 4 + m * 2 + (q >> 1);
#pragma unroll
        for (int ng = 0; ng < 4; ++ng) {
            const int row = pg * 4 + ng;
            const int spres = (row + 2) * 20 + l15 + 2;
            uint2 ru = ((const uint2*)s_in)[(o8r * NIN + spres) * 2 + (q & 1)];
            half4v rv = __builtin_bit_cast(half4v, ru);
            float v[4];
            v[0] = acc2[m][ng][0] + bv.x + (float)rv[0];
            v[1] = acc2[m][ng][1] + bv.y + (float)rv[1];
            v[2] = acc2[m][ng][2] + bv.z + (float)rv[2];
            v[3] = acc2[m][ng][3] + bv.w + (float)rv[3];
            const size_t off = ((size_t)b * HW + (size_t)(y0 + row) * W + x0 + l15) * 64 + oc0;
            half4v hv = { (_Float16)v[0], (_Float16)v[1], (_Float16)v[2], (_Float16)v[3] };
            *(half4v*)&out[off] = hv;
            if (STATS) {
#pragma unroll
                for (int r = 0; r < 4; ++r) {
                    lmax[m][r] = fmaxf(lmax[m][r], v[r]);
                    lsum[m][r] += v[r];
                }
            }
        }
    }
    if (STATS) {
        // reduce over the 16 cols (l15) within each q-group
#pragma unroll
        for (int msk = 1; msk < 16; msk <<= 1) {
#pragma unroll
            for (int m = 0; m < 2; ++m)
#pragma unroll
                for (int r = 0; r < 4; ++r) {
                    lmax[m][r] = fmaxf(lmax[m][r], __shfl_xor(lmax[m][r], msk));
                    lsum[m][r] += __shfl_xor(lsum[m][r], msk);
                }
        }
        if (l15 == 0) {
#pragma unroll
            for (int m = 0; m < 2; ++m)
#pragma unroll
                for (int r = 0; r < 4; ++r) {
                    int oc = og * 32 + m * 16 + q * 4 + r;
                    s_stat[0][wv][oc] = lmax[m][r];
                    s_stat[1][wv][oc] = lsum[m][r];
                }
        }
        __syncthreads();
        if (tid < 64) {
            int oc = tid;
            int w0i = (oc < 32) ? 0 : 4;
            float mv = s_stat[0][w0i][oc], sv = s_stat[1][w0i][oc];
#pragma unroll
            for (int k = 1; k < 4; ++k) {
                mv = fmaxf(mv, s_stat[0][w0i + k][oc]);
                sv += s_stat[1][w0i + k][oc];
            }
            atomicMax(&umax[b * 64 + oc], fenc(mv));
            atomicAdd(&fsum[b * 64 + oc], sv);
        }
    }
}

// ---------------------------------------------------------------------------
// MFE branch-1 fused, oc-split: t5/t3/t1 = lrelu(convKa(o)). B staged once.
// ---------------------------------------------------------------------------
__global__ __launch_bounds__(256, 2) void mfe1_kernel(
    const _Float16* __restrict__ in,
    const _Float16* __restrict__ w5, const _Float16* __restrict__ w3,
    const _Float16* __restrict__ w1,
    const float* __restrict__ b5, const float* __restrict__ b3,
    const float* __restrict__ b1,
    _Float16* __restrict__ t5, _Float16* __restrict__ t3, _Float16* __restrict__ t1)
{
    constexpr int IWs = 20, NPX = 240, NPXP = 241;
    __shared__ __align__(16) unsigned int s_b[NPXP * 32];

    const int tid = threadIdx.x;
    const int bx = blockIdx.x, b = blockIdx.y;
    const int y0 = (bx >> 3) * 8, x0 = (bx & 7) * 16;
    const int lane = tid & 63, wv = tid >> 6;
    const int ph = wv & 1, og = wv >> 1;
    const int l15 = lane & 15, q = lane >> 4;

    uint4 a0[4], a1[4];
    loadAo(w5, og, q, l15, a0);

    for (int idx = tid; idx < NPX * 8; idx += 256) {
        int px = idx >> 3, o8 = idx & 7;
        int r = px / IWs, cix = px - r * IWs;
        int gy = y0 + r - 2, gx = x0 + cix - 2;
        uint4 v = {0u, 0u, 0u, 0u};
        if (gy >= 0 && gy < H && gx >= 0 && gx < W)
            v = *(const uint4*)&in[((size_t)b * HW + (size_t)gy * W + gx) * 64 + o8 * 8];
        ((uint4*)s_b)[o8 * NPXP + px] = v;
    }
    __syncthreads();

    floatx4 acc[2][4] = {};
    const floatx4 z4 = {0.f, 0.f, 0.f, 0.f};

    auto epi = [&](const float* bias, _Float16* outp, bool reset) {
#pragma unroll
        for (int m = 0; m < 2; ++m) {
            const int oc0 = og * 32 + m * 16 + q * 4;
            const float4 bv = *(const float4*)(bias + oc0);
#pragma unroll
            for (int ng = 0; ng < 4; ++ng) {
                const int y = y0 + 4 * ph + ng, x = x0 + l15;
                const size_t off = ((size_t)b * HW + (size_t)y * W + x) * 64 + oc0;
                float v[4] = { acc[m][ng][0] + bv.x, acc[m][ng][1] + bv.y,
                               acc[m][ng][2] + bv.z, acc[m][ng][3] + bv.w };
#pragma unroll
                for (int r = 0; r < 4; ++r) v[r] = v[r] > 0.f ? v[r] : 0.01f * v[r];
                half4v hv = { (_Float16)v[0], (_Float16)v[1], (_Float16)v[2], (_Float16)v[3] };
                *(half4v*)&outp[off] = hv;
                if (reset) acc[m][ng] = z4;
            }
        }
    };

#pragma unroll
    for (int g = 0; g < 25; ++g) {
        uint4* cur = (g & 1) ? a1 : a0;
        uint4* nxt = (g & 1) ? a0 : a1;
        const _Float16* np = (g + 1 < 25) ? w5 + (size_t)(g + 1) * 4096 : w3;
        loadAo(np, og, q, l15, nxt);
        __builtin_amdgcn_sched_barrier(0);
        mstep_og<IWs, NPXP>(s_b, cur, acc, ph, l15, q, g / 5, g % 5, 0);
    }
    epi(b5, t5, true);
#pragma unroll
    for (int g = 0; g < 9; ++g) {
        uint4* cur = (g & 1) ? a0 : a1;
        uint4* nxt = (g & 1) ? a1 : a0;
        const _Float16* np = (g + 1 < 9) ? w3 + (size_t)(g + 1) * 4096 : w1;
        loadAo(np, og, q, l15, nxt);
        __builtin_amdgcn_sched_barrier(0);
        mstep_og<IWs, NPXP>(s_b, cur, acc, ph, l15, q, g / 3, g % 3, 1);
    }
    epi(b3, t3, true);
    mstep_og<IWs, NPXP>(s_b, a0, acc, ph, l15, q, 0, 0, 2);
    epi(b1, t1, false);
}

// ---------------------------------------------------------------------------
// MFE branch-2 fused + channel gate, oc-split: o = Cg*(conv5b(t5)+conv3b(t3)
// +conv1b(t1)+biases). Stats read from fused-res atomics (umax/fsum).
// ---------------------------------------------------------------------------
__global__ __launch_bounds__(256, 2) void mfe2_kernel(
    const _Float16* __restrict__ t5in, const _Float16* __restrict__ t3in,
    const _Float16* __restrict__ t1in,
    const _Float16* __restrict__ w5, const _Float16* __restrict__ w3,
    const _Float16* __restrict__ w1,
    const float* __restrict__ b5, const float* __restrict__ b3,
    const float* __restrict__ b1,
    const unsigned* __restrict__ umax, const float* __restrict__ fsum,
    const float* __restrict__ caw1, const float* __restrict__ caw2,
    const float* __restrict__ fcwj, const float* __restrict__ fcbj,
    _Float16* __restrict__ o)
{
    constexpr int IWs = 20, NPX = 240, NPXP = 241;
    __shared__ __align__(16) unsigned int s_b[NPXP * 32];
    __shared__ float s_hid[8];

    const int tid = threadIdx.x;
    const int bx = blockIdx.x, b = blockIdx.y;
    const int y0 = (bx >> 3) * 8, x0 = (bx & 7) * 16;
    const int lane = tid & 63, wv = tid >> 6;
    const int ph = wv & 1, og = wv >> 1;
    const int l15 = lane & 15, q = lane >> 4;

    auto stageB = [&](const _Float16* __restrict__ src) {
        for (int idx = tid; idx < NPX * 8; idx += 256) {
            int px = idx >> 3, o8 = idx & 7;
            int r = px / IWs, cix = px - r * IWs;
            int gy = y0 + r - 2, gx = x0 + cix - 2;
            uint4 v = {0u, 0u, 0u, 0u};
            if (gy >= 0 && gy < H && gx >= 0 && gx < W)
                v = *(const uint4*)&src[((size_t)b * HW + (size_t)gy * W + gx) * 64 + o8 * 8];
            ((uint4*)s_b)[o8 * NPXP + px] = v;
        }
    };

    uint4 a0[4], a1[4];
    loadAo(w5, og, q, l15, a0);

    stageB(t5in);
    if (tid < 8) {
        int which = tid >> 2, hh = tid & 3;
        float s = 0.f;
        for (int i = 0; i < 64; ++i) {
            float val = which ? (fsum[b * 64 + i] * (1.f / HW)) : fdec(umax[b * 64 + i]);
            s += caw1[hh * 64 + i] * val;
        }
        s_hid[tid] = fmaxf(s, 0.f);
    }
    __syncthreads();

    floatx4 acc[2][4] = {};

#pragma unroll
    for (int g = 0; g < 25; ++g) {
        uint4* cur = (g & 1) ? a1 : a0;
        uint4* nxt = (g & 1) ? a0 : a1;
        const _Float16* np = (g + 1 < 25) ? w5 + (size_t)(g + 1) * 4096 : w3;
        loadAo(np, og, q, l15, nxt);
        __builtin_amdgcn_sched_barrier(0);
        mstep_og<IWs, NPXP>(s_b, cur, acc, ph, l15, q, g / 5, g % 5, 0);
    }
    __syncthreads();
    stageB(t3in);
    __syncthreads();
#pragma unroll
    for (int g = 0; g < 9; ++g) {
        uint4* cur = (g & 1) ? a0 : a1;
        uint4* nxt = (g & 1) ? a1 : a0;
        const _Float16* np = (g + 1 < 9) ? w3 + (size_t)(g + 1) * 4096 : w1;
        loadAo(np, og, q, l15, nxt);
        __builtin_amdgcn_sched_barrier(0);
        mstep_og<IWs, NPXP>(s_b, cur, acc, ph, l15, q, g / 3, g % 3, 1);
    }
    __syncthreads();
    stageB(t1in);
    __syncthreads();
    mstep_og<IWs, NPXP>(s_b, a0, acc, ph, l15, q, 0, 0, 2);

    // epilogue: Cg from SE hidden + FC1, then o = Cg*(acc + b5+b3+b1)
    float hs[4];
#pragma unroll
    for (int hh = 0; hh < 4; ++hh) hs[hh] = s_hid[hh] + s_hid[4 + hh];
    const float fw0 = fcwj[0], fw1 = fcwj[1], fb0 = fcbj[0], fb1 = fcbj[1];
#pragma unroll
    for (int m = 0; m < 2; ++m) {
        const int oc0 = og * 32 + m * 16 + q * 4;
        const float4 bv5 = *(const float4*)(b5 + oc0);
        const float4 bv3 = *(const float4*)(b3 + oc0);
        const float4 bv1 = *(const float4*)(b1 + oc0);
        float bs[4] = { bv5.x + bv3.x + bv1.x, bv5.y + bv3.y + bv1.y,
                        bv5.z + bv3.z + bv1.z, bv5.w + bv3.w + bv1.w };
        float cg[4];
#pragma unroll
        for (int r = 0; r < 4; ++r) {
            const float4 w2 = *(const float4*)(caw2 + (oc0 + r) * 4);
            float s = w2.x * hs[0] + w2.y * hs[1] + w2.z * hs[2] + w2.w * hs[3];
            float xll = 1.f / (1.f + expf(-s));
            cg[r] = fw1 * (fw0 * xll + fb0) + fb1;
        }
#pragma unroll
        for (int ng = 0; ng < 4; ++ng) {
            const int y = y0 + 4 * ph + ng, x = x0 + l15;
            const size_t off = ((size_t)b * HW + (size_t)y * W + x) * 64 + oc0;
            float v[4];
#pragma unroll
            for (int r = 0; r < 4; ++r) v[r] = (acc[m][ng][r] + bs[r]) * cg[r];
            half4v hv = { (_Float16)v[0], (_Float16)v[1], (_Float16)v[2], (_Float16)v[3] };
            *(half4v*)&o[off] = hv;
        }
    }
}

// out(fp32 NCHW) = o(fp16 NHWC) * map + x, LDS transpose
__global__ __launch_bounds__(256) void final_kernel(
    const _Float16* __restrict__ o, const float* __restrict__ mapp,
    const float* __restrict__ x, float* __restrict__ out)
{
    __shared__ _Float16 s[64 * 72];
    const int b = blockIdx.y;
    const size_t p0 = (size_t)blockIdx.x * 64;
    const int t = threadIdx.x;
#pragma unroll
    for (int k = 0; k < 2; ++k) {
        int idx = k * 256 + t;
        int pxw = idx >> 3, o8 = idx & 7;
        uint4 v = *(const uint4*)&o[((size_t)b * HW + p0 + pxw) * 64 + o8 * 8];
        *(uint4*)&s[pxw * 72 + o8 * 8] = v;
    }
    __syncthreads();
    const int px = t & 63, cg0 = t >> 6;
    const float mv = mapp[(size_t)b * HW + p0 + px];
#pragma unroll
    for (int k = 0; k < 16; ++k) {
        int c = cg0 * 16 + k;
        size_t off = ((size_t)(b * 64 + c)) * HW + p0 + px;
        out[off] = (float)s[px * 72 + c] * mv + x[off];
    }
}

extern "C" void kernel_launch(void* const* d_in, const int* in_sizes, int n_in,
                              void* d_out, int out_size, void* d_ws, size_t ws_size,
                              hipStream_t stream)
{
    const float* x    = (const float*)d_in[0];
    const float* cf1  = (const float*)d_in[1];
    const float* cf2  = (const float*)d_in[2];
    const float* mapp = (const float*)d_in[3];
    const float* rw   = (const float*)d_in[4];
    const float* rb   = (const float*)d_in[5];
    const float* mw1  = (const float*)d_in[6];
    const float* mb1  = (const float*)d_in[7];
    const float* mw3  = (const float*)d_in[8];
    const float* mb3  = (const float*)d_in[9];
    const float* mw5  = (const float*)d_in[10];
    const float* mb5  = (const float*)d_in[11];
    const float* caw1 = (const float*)d_in[12];
    const float* caw2 = (const float*)d_in[13];
    const float* fcw  = (const float*)d_in[14];
    const float* fcb  = (const float*)d_in[15];
    float* out = (float*)d_out;

    _Float16* wta = (_Float16*)d_ws;
    _Float16* hb  = wta + A_TOT;
    _Float16* xh  = hb;              // input; reused as t1 after resblock 0
    _Float16* bA  = hb + TOT;
    _Float16* bB  = hb + 2 * TOT;
    _Float16* t5  = hb + 3 * TOT;
    _Float16* t3  = hb + 4 * TOT;
    unsigned* stat = (unsigned*)(hb + 5 * TOT);  // 5 x (256 umax + 256 fsum)

    wt_kernel<<<dim3((unsigned)(A_TOT / 256)), 256, 0, stream>>>(rw, mw1, mw3, mw5, cf1, cf2, wta);
    init_kernel<<<dim3(10), 256, 0, stream>>>(stat);
    xcvt_kernel<<<dim3(256, B), 256, 0, stream>>>(x, xh);

    const dim3 fgrid(64, B);    // 8x8 tiles of 16x16
    const dim3 mgrid(128, B);   // 16x8 tiles of 8x16

    const _Float16* cur = xh;
    int mfe_j = 0;
    for (int i = 0; i < 9; ++i) {
        _Float16* nxt = (i & 1) ? bB : bA;
        bool isMfe = (i == 1 || i == 3 || i == 5 || i == 7 || i == 8);
        const _Float16* w0a = wta + A_RES + (size_t)(i * 2 + 0) * 4 * 36864;
        const _Float16* w1a = wta + A_RES + (size_t)(i * 2 + 1) * 4 * 36864;
        unsigned* um = stat + (size_t)mfe_j * 512;
        float* fs = (float*)(stat + (size_t)mfe_j * 512 + 256);
        if (isMfe)
            fres_kernel<true><<<fgrid, 512, 0, stream>>>(
                cur, w0a, w1a, rb + (i * 2 + 0) * C, rb + (i * 2 + 1) * C, um, fs, nxt);
        else
            fres_kernel<false><<<fgrid, 512, 0, stream>>>(
                cur, w0a, w1a, rb + (i * 2 + 0) * C, rb + (i * 2 + 1) * C, nullptr, nullptr, nxt);
        cur = nxt;

        if (isMfe) {
            int j = mfe_j++;
            mfe1_kernel<<<mgrid, 256, 0, stream>>>(
                cur,
                wta + A_M5 + (size_t)(j * 2 + 0) * 102400,
                wta + A_M3 + (size_t)(j * 2 + 0) * 36864,
                wta + A_M1 + (size_t)(j * 2 + 0) * 4096,
                mb5 + (j * 2 + 0) * C, mb3 + (j * 2 + 0) * C, mb1 + (j * 2 + 0) * C,
                t5, t3, xh);
            mfe2_kernel<<<mgrid, 256, 0, stream>>>(
                t5, t3, xh,
                wta + A_M5 + (size_t)(j * 2 + 1) * 102400,
                wta + A_M3 + (size_t)(j * 2 + 1) * 36864,
                wta + A_M1 + (size_t)(j * 2 + 1) * 4096,
                mb5 + (j * 2 + 1) * C, mb3 + (j * 2 + 1) * C, mb1 + (j * 2 + 1) * C,
                um, fs, caw1 + j * 4 * C, caw2 + j * C * 4,
                fcw + j * 2, fcb + j * 2, (_Float16*)cur);
        }
    }
    final_kernel<<<dim3(256, B), 256, 0, stream>>>(cur, mapp, x, out);
}